// Round 7
// baseline (9326.819 us; speedup 1.0000x reference)
//
#include <hip/hip_runtime.h>
#include <math.h>

// ---------------------------------------------------------------------------
// RGN: 2-layer biLSTM (T=512,B=32,H=800) -> linear/softmax/dihedral -> NeRF chain
// Round 7 (= R6 resubmit; R6 hit GPUAcquisitionTimeout, never ran).
// Aggregator-based barrier to kill the LLC poll storm.
//   R5 post-mortem: bypass coherence halved time, but 199 blocks x 100-line
//   polling ~= 70 Gtxn/s at the LLC throttles the critical path.
//   Now: workers store own flag (own cacheline) and poll ONE epoch word
//   (thread 0 only); one aggregator block per direction polls the 100 flags
//   and publishes the epoch. Poll traffic cut ~50x.
//   Compute structure unchanged (register-resident f16 MFMA weights,
//   bypass-atomic recurrent state, cached static data).
// ---------------------------------------------------------------------------

#define TT 512
#define BB 32
#define HH 800
#define DIN 41
#define XPAD 64                // x padded to 64 cols (zeros) -> 2 clean k-steps
#define KROW 1600              // h row length in k (both directions packed)
#define NBLK 200
#define BPD 100                // blocks per direction
#define FPAD 16                // one 64B cacheline per flag/epoch word

typedef _Float16 f16;
typedef _Float16 half8 __attribute__((ext_vector_type(8)));
typedef float floatx4 __attribute__((ext_vector_type(4)));

// ---------------- workspace layout (float-slot offsets), total ~107 MB -----
// u32[0..6400):   flags [kernel(2)][dir(2)][BPD(100)][FPAD]
// u32[6400..6464): epochs [kernel(2)][dir(2)][FPAD]
#define OFF_XT   8192                       // f16 [512][32][64]    (524288 slots)
#define OFF_H1   (OFF_XT + 524288)          // f16 [512][32][1600]  (13107200 slots)
#define OFF_H2   (OFF_H1 + 13107200)        // f16 [512][32][1600]  (13107200 slots)
#define OFF_ANG  (OFF_H2 + 13107200)        // f32 [512][32][3]     (49152)
#define OFF_SIN  (OFF_ANG + 49152)
#define OFF_COS  (OFF_SIN + 64)

__device__ __forceinline__ float sigm(float x) { return 1.0f / (1.0f + expf(-x)); }

union U64H8 { unsigned long long u[2]; half8 h; };

// 16B load/store through the coherent point (LLC), no cache maintenance.
__device__ __forceinline__ half8 ald16(const f16* p) {
    U64H8 x;
    x.u[0] = __hip_atomic_load((const unsigned long long*)p,     __ATOMIC_RELAXED, __HIP_MEMORY_SCOPE_AGENT);
    x.u[1] = __hip_atomic_load((const unsigned long long*)p + 1, __ATOMIC_RELAXED, __HIP_MEMORY_SCOPE_AGENT);
    return x.h;
}
__device__ __forceinline__ void ast16(f16* p, half8 v) {
    U64H8 x; x.h = v;
    __hip_atomic_store((unsigned long long*)p,     x.u[0], __ATOMIC_RELAXED, __HIP_MEMORY_SCOPE_AGENT);
    __hip_atomic_store((unsigned long long*)p + 1, x.u[1], __ATOMIC_RELAXED, __HIP_MEMORY_SCOPE_AGENT);
}

// Aggregator: wave 0 polls the direction's BPD flags, min-reduces, publishes
// the min into the epoch word. Monotonic (flags only grow) -> lap-safe.
__device__ __forceinline__ void aggregator(unsigned* flags, unsigned* epoch) {
    if (threadIdx.x >= 64) return;
    unsigned e = 1;
    while (e <= TT) {
        unsigned v = 0xffffffffu;
        for (int i = (int)threadIdx.x; i < BPD; i += 64) {
            const unsigned f = __hip_atomic_load(&flags[i * FPAD], __ATOMIC_RELAXED, __HIP_MEMORY_SCOPE_AGENT);
            v = (f < v) ? f : v;
        }
#pragma unroll
        for (int off = 1; off < 64; off <<= 1) {
            const unsigned o = (unsigned)__shfl_xor((int)v, off, 64);
            v = (o < v) ? o : v;
        }
        if (v >= e) {
            if (threadIdx.x == 0)
                __hip_atomic_store(epoch, v, __ATOMIC_RELAXED, __HIP_MEMORY_SCOPE_AGENT);
            e = v + 1;
        } else {
            __builtin_amdgcn_s_sleep(2);
        }
    }
}

// Worker barrier: store own flag (preceding __syncthreads drains vmcnt, so
// all bypass h-stores are LLC-visible first), then poll the single epoch word.
__device__ __forceinline__ void fbar(unsigned* flags, const unsigned* epoch,
                                     int myidx, unsigned target) {
    __syncthreads();
    if (threadIdx.x == 0) {
        __hip_atomic_store(&flags[myidx * FPAD], target, __ATOMIC_RELAXED, __HIP_MEMORY_SCOPE_AGENT);
        while (__hip_atomic_load(epoch, __ATOMIC_RELAXED, __HIP_MEMORY_SCOPE_AGENT) < target)
            __builtin_amdgcn_s_sleep(2);
    }
    __syncthreads();
}

__device__ __forceinline__ half8 cvt8(const float* p) {
    half8 r;
#pragma unroll
    for (int i = 0; i < 8; ++i) r[i] = (f16)p[i];
    return r;
}

// ===========================================================================
// rnn0: layer 0.  K = 64 (xT, cached) + 800 (h1 prev, bypass) per dir.
// Blocks [0,NBLK): workers. Blocks NBLK..NBLK+1: per-direction aggregators.
// ===========================================================================
__global__ __launch_bounds__(256, 1) void rnn0_kernel(
    const f16* __restrict__ xT, f16* __restrict__ h1,
    const float* __restrict__ Wih_f0, const float* __restrict__ Whh_f0, const float* __restrict__ b_f0,
    const float* __restrict__ Wih_b0, const float* __restrict__ Whh_b0, const float* __restrict__ b_b0,
    unsigned* __restrict__ fl, unsigned* __restrict__ ep)
{
    if (blockIdx.x >= NBLK) {
        const int adir = blockIdx.x - NBLK;
        aggregator(fl + adir * BPD * FPAD, ep + adir * FPAD);
        return;
    }

    __shared__ float gbuf[4][32][33];
    __shared__ f16  hbuf[256];

    const int tid  = threadIdx.x;
    const int dir  = blockIdx.x / BPD;
    const int blk  = blockIdx.x % BPD;
    const int j0   = blk * 8;
    const int w    = tid >> 6;          // wave id = k-slice
    const int lane = tid & 63;
    const int l15  = lane & 15;
    const int quad = lane >> 4;
    const int jl   = tid >> 5;          // epilogue: hidden unit 0..7
    const int bb   = tid & 31;          // epilogue: batch

    unsigned* flags = fl + dir * BPD * FPAD;
    const unsigned* epoch = ep + dir * FPAD;

    const float* Wih = dir ? Wih_b0 : Wih_f0;
    const float* Whh = dir ? Whh_b0 : Whh_f0;
    const float* bs  = dir ? b_b0  : b_f0;

    const int kt0 = (w * 27) >> 2;          // 0,6,13,20
    const int kt1 = ((w + 1) * 27) >> 2;    // 6,13,20,27

    half8 afr[2][7];
#pragma unroll
    for (int mt = 0; mt < 2; ++mt) {
        const int r = mt * 16 + l15;
        const int grow = (r >> 3) * HH + j0 + (r & 7);
#pragma unroll
        for (int i = 0; i < 7; ++i) {
            const int ktg = kt0 + i;
            half8 v;
#pragma unroll
            for (int jj = 0; jj < 8; ++jj) v[jj] = (f16)0.f;
            if (ktg < kt1) {
                if (ktg < 2) {          // Wih cols (41 wide, zero-padded to 64)
#pragma unroll
                    for (int jj = 0; jj < 8; ++jj) {
                        const int k = ktg * 32 + quad * 8 + jj;
                        if (k < DIN) v[jj] = (f16)Wih[(size_t)grow * DIN + k];
                    }
                } else {                // Whh cols
                    v = cvt8(Whh + (size_t)grow * HH + (ktg - 2) * 32 + quad * 8);
                }
            }
            afr[mt][i] = v;
        }
    }
    const float bi = bs[0 * HH + j0 + jl], bf = bs[1 * HH + j0 + jl],
                bg = bs[2 * HH + j0 + jl], bo = bs[3 * HH + j0 + jl];

    float creg = 0.0f;
    for (int s = 0; s < TT; ++s) {
        const int t  = dir ? (TT - 1 - s) : s;
        const int tp = dir ? t + 1 : t - 1;
        floatx4 acc[2][2];
        acc[0][0] = (floatx4)0.f; acc[0][1] = (floatx4)0.f;
        acc[1][0] = (floatx4)0.f; acc[1][1] = (floatx4)0.f;

        const f16* xrow = xT + (size_t)t * BB * XPAD;                // static: cached
        const f16* hrow = h1 + (size_t)tp * BB * KROW + dir * HH;    // dynamic: bypass
#pragma unroll
        for (int i = 0; i < 7; ++i) {
            const int ktg = kt0 + i;
            if (ktg < kt1) {
                const bool isx = (ktg < 2);
                if (isx || s > 0) {
                    half8 b0, b1;
                    if (isx) {
                        const f16* p = xrow + ktg * 32 + quad * 8;
                        b0 = *(const half8*)(p + (size_t)l15 * XPAD);
                        b1 = *(const half8*)(p + (size_t)(16 + l15) * XPAD);
                    } else {
                        const f16* p = hrow + (ktg - 2) * 32 + quad * 8;
                        b0 = ald16(p + (size_t)l15 * KROW);
                        b1 = ald16(p + (size_t)(16 + l15) * KROW);
                    }
                    acc[0][0] = __builtin_amdgcn_mfma_f32_16x16x32_f16(afr[0][i], b0, acc[0][0], 0, 0, 0);
                    acc[0][1] = __builtin_amdgcn_mfma_f32_16x16x32_f16(afr[0][i], b1, acc[0][1], 0, 0, 0);
                    acc[1][0] = __builtin_amdgcn_mfma_f32_16x16x32_f16(afr[1][i], b0, acc[1][0], 0, 0, 0);
                    acc[1][1] = __builtin_amdgcn_mfma_f32_16x16x32_f16(afr[1][i], b1, acc[1][1], 0, 0, 0);
                }
            }
        }
        // per-wave partials -> LDS   (D layout: row = quad*4+reg, col = l15)
#pragma unroll
        for (int mt = 0; mt < 2; ++mt)
#pragma unroll
            for (int nt = 0; nt < 2; ++nt)
#pragma unroll
                for (int rg = 0; rg < 4; ++rg)
                    gbuf[w][mt * 16 + quad * 4 + rg][nt * 16 + l15] = acc[mt][nt][rg];
        __syncthreads();
        {   // epilogue: thread (jl, bb)
            float gi_ = bi, gf_ = bf, gc_ = bg, go_ = bo;
#pragma unroll
            for (int ww = 0; ww < 4; ++ww) {
                gi_ += gbuf[ww][jl][bb];
                gf_ += gbuf[ww][8 + jl][bb];
                gc_ += gbuf[ww][16 + jl][bb];
                go_ += gbuf[ww][24 + jl][bb];
            }
            const float cn = sigm(gf_) * creg + sigm(gi_) * tanhf(gc_);
            creg = cn;
            hbuf[bb * 8 + jl] = (f16)(sigm(go_) * tanhf(cn));
        }
        __syncthreads();
        if (tid < BB)
            ast16(h1 + ((size_t)t * BB + tid) * KROW + dir * HH + j0,
                  *(const half8*)(hbuf + tid * 8));
        fbar(flags, epoch, blk, (unsigned)(s + 1));
    }
}

// ===========================================================================
// rnn1: layer 1.  K = 1600 (h1[t], cached) + 800 (h2 prev, bypass).
// ===========================================================================
__global__ __launch_bounds__(256, 1) void rnn1_kernel(
    const f16* __restrict__ h1, f16* __restrict__ h2,
    const float* __restrict__ Wih_f1, const float* __restrict__ Whh_f1, const float* __restrict__ b_f1,
    const float* __restrict__ Wih_b1, const float* __restrict__ Whh_b1, const float* __restrict__ b_b1,
    unsigned* __restrict__ fl, unsigned* __restrict__ ep)
{
    if (blockIdx.x >= NBLK) {
        const int adir = blockIdx.x - NBLK;
        aggregator(fl + adir * BPD * FPAD, ep + adir * FPAD);
        return;
    }

    __shared__ float gbuf[4][32][33];
    __shared__ f16  hbuf[256];

    const int tid  = threadIdx.x;
    const int dir  = blockIdx.x / BPD;
    const int blk  = blockIdx.x % BPD;
    const int j0   = blk * 8;
    const int w    = tid >> 6;
    const int lane = tid & 63;
    const int l15  = lane & 15;
    const int quad = lane >> 4;
    const int jl   = tid >> 5;
    const int bb   = tid & 31;

    unsigned* flags = fl + dir * BPD * FPAD;
    const unsigned* epoch = ep + dir * FPAD;

    const float* Wih = dir ? Wih_b1 : Wih_f1;
    const float* Whh = dir ? Whh_b1 : Whh_f1;
    const float* bs  = dir ? b_b1  : b_f1;

    const int kt0 = (w * 75) >> 2;          // 0,18,37,56
    const int kt1 = ((w + 1) * 75) >> 2;    // 18,37,56,75

    half8 afr[2][19];                       // weight fragments, register-resident
#pragma unroll
    for (int mt = 0; mt < 2; ++mt) {
        const int r = mt * 16 + l15;
        const int grow = (r >> 3) * HH + j0 + (r & 7);
#pragma unroll
        for (int i = 0; i < 19; ++i) {
            const int ktg = kt0 + i;
            half8 v;
#pragma unroll
            for (int jj = 0; jj < 8; ++jj) v[jj] = (f16)0.f;
            if (ktg < kt1) {
                if (ktg < 50) v = cvt8(Wih + (size_t)grow * KROW + ktg * 32 + quad * 8);
                else          v = cvt8(Whh + (size_t)grow * HH + (ktg - 50) * 32 + quad * 8);
            }
            afr[mt][i] = v;
        }
    }
    const float bi = bs[0 * HH + j0 + jl], bf = bs[1 * HH + j0 + jl],
                bg = bs[2 * HH + j0 + jl], bo = bs[3 * HH + j0 + jl];

    float creg = 0.0f;
    for (int s = 0; s < TT; ++s) {
        const int t  = dir ? (TT - 1 - s) : s;
        const int tp = dir ? t + 1 : t - 1;
        floatx4 acc[2][2];
        acc[0][0] = (floatx4)0.f; acc[0][1] = (floatx4)0.f;
        acc[1][0] = (floatx4)0.f; acc[1][1] = (floatx4)0.f;

        const f16* h1row = h1 + (size_t)t * BB * KROW;               // static: cached
        const f16* h2row = h2 + (size_t)tp * BB * KROW + dir * HH;   // dynamic: bypass
#pragma unroll
        for (int i = 0; i < 19; ++i) {
            const int ktg = kt0 + i;
            if (ktg < kt1) {
                const bool isin = (ktg < 50);
                if (isin || s > 0) {
                    half8 b0, b1;
                    if (isin) {
                        const f16* p = h1row + ktg * 32 + quad * 8;
                        b0 = *(const half8*)(p + (size_t)l15 * KROW);
                        b1 = *(const half8*)(p + (size_t)(16 + l15) * KROW);
                    } else {
                        const f16* p = h2row + (ktg - 50) * 32 + quad * 8;
                        b0 = ald16(p + (size_t)l15 * KROW);
                        b1 = ald16(p + (size_t)(16 + l15) * KROW);
                    }
                    acc[0][0] = __builtin_amdgcn_mfma_f32_16x16x32_f16(afr[0][i], b0, acc[0][0], 0, 0, 0);
                    acc[0][1] = __builtin_amdgcn_mfma_f32_16x16x32_f16(afr[0][i], b1, acc[0][1], 0, 0, 0);
                    acc[1][0] = __builtin_amdgcn_mfma_f32_16x16x32_f16(afr[1][i], b0, acc[1][0], 0, 0, 0);
                    acc[1][1] = __builtin_amdgcn_mfma_f32_16x16x32_f16(afr[1][i], b1, acc[1][1], 0, 0, 0);
                }
            }
        }
#pragma unroll
        for (int mt = 0; mt < 2; ++mt)
#pragma unroll
            for (int nt = 0; nt < 2; ++nt)
#pragma unroll
                for (int rg = 0; rg < 4; ++rg)
                    gbuf[w][mt * 16 + quad * 4 + rg][nt * 16 + l15] = acc[mt][nt][rg];
        __syncthreads();
        {
            float gi_ = bi, gf_ = bf, gc_ = bg, go_ = bo;
#pragma unroll
            for (int ww = 0; ww < 4; ++ww) {
                gi_ += gbuf[ww][jl][bb];
                gf_ += gbuf[ww][8 + jl][bb];
                gc_ += gbuf[ww][16 + jl][bb];
                go_ += gbuf[ww][24 + jl][bb];
            }
            const float cn = sigm(gf_) * creg + sigm(gi_) * tanhf(gc_);
            creg = cn;
            hbuf[bb * 8 + jl] = (f16)(sigm(go_) * tanhf(cn));
        }
        __syncthreads();
        if (tid < BB)
            ast16(h2 + ((size_t)t * BB + tid) * KROW + dir * HH + j0,
                  *(const half8*)(hbuf + tid * 8));
        fbar(flags, epoch, blk, (unsigned)(s + 1));
    }
}

// ---------------------------------------------------------------------------
// prep: xT f16 [t][b][64] zero-padded, sin/cos tables, zero flags + epochs
__global__ void prep_kernel(const float* __restrict__ x, const float* __restrict__ alphabet,
                            f16* __restrict__ xT, float* __restrict__ sin_t,
                            float* __restrict__ cos_t, unsigned* __restrict__ fl) {
    const int gid = blockIdx.x * blockDim.x + threadIdx.x;
    const int nth = gridDim.x * blockDim.x;
    for (int idx = gid; idx < TT * BB * XPAD; idx += nth) {
        const int tb = idx >> 6;            // t*32+b
        const int i  = idx & 63;
        xT[idx] = (i < DIN) ? (f16)x[(size_t)tb * DIN + i] : (f16)0.f;
    }
    if (gid < 60) { sin_t[gid] = sinf(alphabet[gid]); cos_t[gid] = cosf(alphabet[gid]); }
    if (gid < 2 * 2 * BPD * FPAD + 4 * FPAD) fl[gid] = 0u;
}

// logits -> softmax -> dihedral angles (h2 f16, [t][b][k])
__global__ __launch_bounds__(640, 1) void head_kernel(
    const f16* __restrict__ h2, const float* __restrict__ Wl, const float* __restrict__ bl,
    const float* __restrict__ sin_t, const float* __restrict__ cos_t,
    float* __restrict__ angles) {
    __shared__ float pl[20][33];
    __shared__ float mx[32];
    const int t = blockIdx.x;
    const int a = threadIdx.x / 32;
    const int b = threadIdx.x & 31;
    if (a < 20) {
        float acc = bl[a];
        const float* wr = Wl + (size_t)a * KROW;
        const f16*   hr = h2 + ((size_t)t * BB + b) * KROW;
        for (int k8 = 0; k8 < KROW / 8; ++k8) {
            const half8 hv = *(const half8*)(hr + k8 * 8);
#pragma unroll
            for (int j = 0; j < 8; ++j) acc = fmaf(wr[k8 * 8 + j], (float)hv[j], acc);
        }
        pl[a][b] = acc;
    }
    __syncthreads();
    if (threadIdx.x < 32) {
        float m = pl[0][threadIdx.x];
        for (int i = 1; i < 20; ++i) m = fmaxf(m, pl[i][threadIdx.x]);
        mx[threadIdx.x] = m;
    }
    __syncthreads();
    if (a < 20) pl[a][b] = expf(pl[a][b] - mx[b]);
    __syncthreads();
    if (threadIdx.x < 96) {
        const int c = threadIdx.x / 32, b2 = threadIdx.x & 31;
        float y = 0.f, xx = 0.f;
        for (int i = 0; i < 20; ++i) {
            const float e = pl[i][b2];
            y  = fmaf(e, sin_t[i * 3 + c], y);
            xx = fmaf(e, cos_t[i * 3 + c], xx);
        }
        angles[((size_t)t * BB + b2) * 3 + c] = atan2f(y, xx);
    }
}

// sequential NeRF coordinate extension, one lane per batch element
__global__ void coords_kernel(const float* __restrict__ angles, float* __restrict__ out) {
    const int b = threadIdx.x;
    if (b >= BB) return;
    const float rs[3]  = {1.458f, 1.525f, 1.33f};
    const float ths[3] = {2.124f, 1.941f, 2.028f};
    float ct[3], st[3];
#pragma unroll
    for (int k = 0; k < 3; ++k) { ct[k] = cosf(ths[k]); st[k] = sinf(ths[k]); }
    float pax = 0.f,     pay = 0.f, paz = 0.f;
    float pbx = 1.458f,  pby = 0.f, pbz = 0.f;
    float pcx = 2.f,     pcy = 1.f, pcz = 0.f;
    for (int n = 0; n < 3 * TT; ++n) {
        const int t = n / 3;
        const int k = n - 3 * t;
        const float phi = angles[((size_t)t * BB + b) * 3 + k];
        float ux = pcx - pbx, uy = pcy - pby, uz = pcz - pbz;
        const float il = rsqrtf(ux * ux + uy * uy + uz * uz);
        const float bcx = ux * il, bcy = uy * il, bcz = uz * il;
        const float wx = pbx - pax, wy = pby - pay, wz = pbz - paz;
        float cx = wy * bcz - wz * bcy, cy = wz * bcx - wx * bcz, cz = wx * bcy - wy * bcx;
        const float iln = rsqrtf(cx * cx + cy * cy + cz * cz);
        const float nx = cx * iln, ny = cy * iln, nz = cz * iln;
        const float mxv = ny * bcz - nz * bcy, myv = nz * bcx - nx * bcz, mzv = nx * bcy - ny * bcx;
        float sp, cp;
        __sincosf(phi, &sp, &cp);
        const float rr = rs[k], cth = ct[k], sth = st[k];
        const float dx = pcx - rr * cth * bcx + rr * sth * (cp * mxv + sp * nx);
        const float dy = pcy - rr * cth * bcy + rr * sth * (cp * myv + sp * ny);
        const float dz = pcz - rr * cth * bcz + rr * sth * (cp * mzv + sp * nz);
        float* o = out + ((size_t)n * BB + b) * 3;
        o[0] = dx; o[1] = dy; o[2] = dz;
        pax = pbx; pay = pby; paz = pbz;
        pbx = pcx; pby = pcy; pbz = pcz;
        pcx = dx;  pcy = dy;  pcz = dz;
    }
}

// ---------------------------------------------------------------------------
extern "C" void kernel_launch(void* const* d_in, const int* in_sizes, int n_in,
                              void* d_out, int out_size, void* d_ws, size_t ws_size,
                              hipStream_t stream) {
    (void)in_sizes; (void)n_in; (void)out_size; (void)ws_size;
    const float* x      = (const float*)d_in[0];
    const float* Wih_f0 = (const float*)d_in[1];
    const float* Whh_f0 = (const float*)d_in[2];
    const float* b_f0   = (const float*)d_in[3];
    const float* Wih_b0 = (const float*)d_in[4];
    const float* Whh_b0 = (const float*)d_in[5];
    const float* b_b0   = (const float*)d_in[6];
    const float* Wih_f1 = (const float*)d_in[7];
    const float* Whh_f1 = (const float*)d_in[8];
    const float* b_f1   = (const float*)d_in[9];
    const float* Wih_b1 = (const float*)d_in[10];
    const float* Whh_b1 = (const float*)d_in[11];
    const float* b_b1   = (const float*)d_in[12];
    const float* Wl     = (const float*)d_in[13];
    const float* bl     = (const float*)d_in[14];
    const float* alphabet = (const float*)d_in[15];

    float* ws = (float*)d_ws;
    unsigned* fl0 = (unsigned*)d_ws;                       // rnn0 flags [2][100][16]
    unsigned* fl1 = (unsigned*)d_ws + 2 * BPD * FPAD;      // rnn1 flags [2][100][16]
    unsigned* ep0 = (unsigned*)d_ws + 4 * BPD * FPAD;      // rnn0 epochs [2][16]
    unsigned* ep1 = ep0 + 2 * FPAD;                        // rnn1 epochs [2][16]
    f16*   xT     = (f16*)(ws + OFF_XT);
    f16*   h1     = (f16*)(ws + OFF_H1);
    f16*   h2     = (f16*)(ws + OFF_H2);
    float* angles = ws + OFF_ANG;
    float* sin_t  = ws + OFF_SIN;
    float* cos_t  = ws + OFF_COS;

    prep_kernel<<<1024, 256, 0, stream>>>(x, alphabet, xT, sin_t, cos_t, (unsigned*)d_ws);
    rnn0_kernel<<<NBLK + 2, 256, 0, stream>>>(xT, h1,
        Wih_f0, Whh_f0, b_f0, Wih_b0, Whh_b0, b_b0, fl0, ep0);
    rnn1_kernel<<<NBLK + 2, 256, 0, stream>>>(h1, h2,
        Wih_f1, Whh_f1, b_f1, Wih_b1, Whh_b1, b_b1, fl1, ep1);
    head_kernel<<<TT, 640, 0, stream>>>(h2, Wl, bl, sin_t, cos_t, angles);
    coords_kernel<<<1, 64, 0, stream>>>(angles, (float*)d_out);
}